// Round 11
// baseline (4203.129 us; speedup 1.0000x reference)
//
#include <hip/hip_runtime.h>
#include <cstdint>

typedef __bf16 bf16x8 __attribute__((ext_vector_type(8)));
typedef float  f32x4  __attribute__((ext_vector_type(4)));

union U4B { uint4 u; bf16x8 b; };
__device__ __forceinline__ bf16x8 as_bf(uint4 u) { U4B x; x.u = u; return x.b; }

// float -> bf16 bits, round-to-nearest-even (finite inputs)
__device__ __forceinline__ unsigned short f2b(float x) {
  unsigned int u = __float_as_uint(x);
  unsigned int r = (u + 0x7fffu + ((u >> 16) & 1u)) >> 16;
  return (unsigned short)r;
}
__device__ __forceinline__ float b2f(unsigned int bits_lo16) {
  return __uint_as_float(bits_lo16 << 16);
}

__device__ __forceinline__ float sigm(float x) {
  float e = __builtin_amdgcn_exp2f(x * -1.4426950408889634f);
  return __builtin_amdgcn_rcpf(1.0f + e);
}
__device__ __forceinline__ float tanh_fast(float x) {
  float e = __builtin_amdgcn_exp2f(x * 2.8853900817779268f);
  return 1.0f - 2.0f * __builtin_amdgcn_rcpf(e + 1.0f);
}

// k-permutation: physical k' <-> original h-unit u.
// writer lane (kg,wid,m) writes physical k = kg*64 + wid*8 + m  (contiguous in m)
// so original u = wid*32 + m*4 + kg = ((k>>3)&7)*32 + (k&7)*4 + (k>>6)
__device__ __forceinline__ int kperm_u(int k) {
  return ((k >> 3) & 7) * 32 + (k & 7) * 4 + (k >> 6);
}

// ---------------- prep: build permuted bf16 weight layouts in ws ----------------
// recT [1024 col'][256 k'] : col' = 4u+g ; k-axis in u'-permuted order
// kb2  [128 ch][1024 col'] : (kernel + bias), col' permutation only
// dwT  [128 class][256 k'] : dense_w transposed, k-axis u'-permuted
__global__ void prep_kernel(const float* __restrict__ rec,
                            const float* __restrict__ kern,
                            const float* __restrict__ bias,
                            const float* __restrict__ dw,
                            unsigned short* __restrict__ recT,
                            unsigned short* __restrict__ kb2,
                            unsigned short* __restrict__ dwT) {
  int id = blockIdx.x * 256 + threadIdx.x;
  if (id < 262144) {                       // 1024*256
    int colp = id >> 8, k = id & 255;
    int u = kperm_u(k);
    int oc = (colp >> 2) + 256 * (colp & 3);
    recT[colp * 256 + k] = f2b(rec[u * 1024 + oc]);
  } else if (id < 262144 + 131072) {       // 128*1024
    int i = id - 262144;
    int ch = i >> 10, colp = i & 1023;
    int oc = (colp >> 2) + 256 * (colp & 3);
    kb2[ch * 1024 + colp] = f2b(kern[ch * 1024 + oc] + bias[oc]);
  } else {                                 // 128*256
    int i = id - 262144 - 131072;
    int cls = i >> 8, k = i & 255;
    int u = kperm_u(k);
    dwT[cls * 256 + k] = f2b(dw[u * 128 + cls]);
  }
}

// ---------------- main persistent LSTM kernel ----------------
// 64 blocks x 512 threads (8 waves; waves_per_eu(2,2)). Block owns 16 batch
// rows for all 512 steps. Wave wid owns gate-cols' [wid*128, wid*128+128)
// = 8 m-tiles, ALL EIGHT resident in AGPRs (af[8][8] = 256 accum regs/wave).
// ZERO per-step A traffic. h in LDS: row stride 288 shorts; XOR swizzle
// applied to the FULL within-row byte offset on BOTH sides (rule #21):
//   read  : row*576 + ((k*64 + kg*16)   ^ ((row&7)<<4))
//   write : row*576 + ((kg*128 + wid*16) ^ ((row&7)<<4))
// Both are 8-lanes-per-16B-phase balanced = minimal for b128. h stored in
// u'-permuted unit order so each lane's 8 outputs are one b128 write; the
// recT/dwT k-axes carry the same permutation (exact relabeling).
__global__ __launch_bounds__(512)
__attribute__((amdgpu_waves_per_eu(2, 2)))
void lstm_kernel(
    const unsigned short* __restrict__ recT,
    const unsigned short* __restrict__ kb2,
    const unsigned short* __restrict__ dwT,
    const int* __restrict__ x,
    const float* __restrict__ dense_b,
    float* __restrict__ out) {
  __shared__ unsigned short h_buf[2][16][288];  // 18.4 KB, swizzled layout
  __shared__ float l_lds[16][132];

  const int tid   = threadIdx.x;
  const int lane  = tid & 63;
  const int wid   = tid >> 6;      // 0..7
  const int row16 = lane & 15;     // batch row within tile
  const int kg    = lane >> 4;     // 0..3
  const int rbase = blockIdx.x << 4;

  // ---- ALL of this wave's A into AGPRs, loaded once ----
  const unsigned short* recBase = recT + ((wid * 128 + row16) * 256 + kg * 8);
  uint4 af[8][8];
#pragma unroll
  for (int m = 0; m < 8; ++m)
#pragma unroll
    for (int k = 0; k < 8; ++k) {
      af[m][k] = *(const uint4*)(recBase + m * 4096 + k * 32);
      asm volatile("" : "+a"(af[m][k].x), "+a"(af[m][k].y),
                        "+a"(af[m][k].z), "+a"(af[m][k].w));
    }

  // zero both h buffers
  for (int e = tid; e < 2 * 16 * 288 / 8; e += 512)
    ((uint4*)h_buf)[e] = uint4{0, 0, 0, 0};

  float c_state[8];
#pragma unroll
  for (int m = 0; m < 8; ++m) c_state[m] = 0.0f;

  const int* xrow = x + (rbase + row16) * 512;
  int idx = xrow[0];

  char* lds = (char*)&h_buf[0][0][0];
  const unsigned swz  = (unsigned)((row16 & 7) << 4);
  const unsigned rowB = (unsigned)(row16 * 576);
  const unsigned kgo  = (unsigned)(kg * 16);
  const unsigned wrOff = rowB + (((unsigned)(kg * 128 + wid * 16)) ^ swz);

  __syncthreads();

  int cur = 0;
#pragma unroll 1
  for (int t = 0; t < 512; ++t) {
    // kq gather for this step (consumed ~60 instrs later at the gate phase)
    const unsigned short* kb = kb2 + (idx * 1024 + wid * 128 + kg * 4);
    uint2 kq[8];
#pragma unroll
    for (int m = 0; m < 8; ++m) kq[m] = *(const uint2*)(kb + m * 16);
    int idx_next = xrow[(t + 1 < 512) ? t + 1 : 511];

    // GEMM: 8 hf reads, 64 MFMAs, all A-operands from AGPRs
    const char* hrdRow = lds + cur * 9216 + rowB;
    f32x4 acc[8];
#pragma unroll
    for (int m = 0; m < 8; ++m) acc[m] = f32x4{0.f, 0.f, 0.f, 0.f};
#pragma unroll
    for (int k = 0; k < 8; ++k) {
      uint4 hf = *(const uint4*)(hrdRow + ((((unsigned)(k * 64)) + kgo) ^ swz));
      acc[0] = __builtin_amdgcn_mfma_f32_16x16x32_bf16(as_bf(af[0][k]), as_bf(hf), acc[0], 0, 0, 0);
      acc[1] = __builtin_amdgcn_mfma_f32_16x16x32_bf16(as_bf(af[1][k]), as_bf(hf), acc[1], 0, 0, 0);
      acc[2] = __builtin_amdgcn_mfma_f32_16x16x32_bf16(as_bf(af[2][k]), as_bf(hf), acc[2], 0, 0, 0);
      acc[3] = __builtin_amdgcn_mfma_f32_16x16x32_bf16(as_bf(af[3][k]), as_bf(hf), acc[3], 0, 0, 0);
      acc[4] = __builtin_amdgcn_mfma_f32_16x16x32_bf16(as_bf(af[4][k]), as_bf(hf), acc[4], 0, 0, 0);
      acc[5] = __builtin_amdgcn_mfma_f32_16x16x32_bf16(as_bf(af[5][k]), as_bf(hf), acc[5], 0, 0, 0);
      acc[6] = __builtin_amdgcn_mfma_f32_16x16x32_bf16(as_bf(af[6][k]), as_bf(hf), acc[6], 0, 0, 0);
      acc[7] = __builtin_amdgcn_mfma_f32_16x16x32_bf16(as_bf(af[7][k]), as_bf(hf), acc[7], 0, 0, 0);
    }

    // gates; pack 8 new h (contiguous units in u'-layout) -> one b128 write
    unsigned hw[4];
#pragma unroll
    for (int p = 0; p < 4; ++p) {
      unsigned short hb[2];
#pragma unroll
      for (int q = 0; q < 2; ++q) {
        const int m = p * 2 + q;
        float zi = acc[m][0] + b2f(kq[m].x & 0xffffu);
        float zf = acc[m][1] + b2f(kq[m].x >> 16);
        float zg = acc[m][2] + b2f(kq[m].y & 0xffffu);
        float zo = acc[m][3] + b2f(kq[m].y >> 16);
        float c  = sigm(zf) * c_state[m] + sigm(zi) * tanh_fast(zg);
        c_state[m] = c;
        hb[q] = f2b(sigm(zo) * tanh_fast(c));
      }
      hw[p] = (unsigned)hb[0] | ((unsigned)hb[1] << 16);
    }
    *(uint4*)(lds + (cur ^ 1) * 9216 + wrOff) = uint4{hw[0], hw[1], hw[2], hw[3]};

    __syncthreads();
    cur ^= 1;
    idx = idx_next;
  }

  // ---- final dense (MFMA) + softmax; final h is in buffer 0 (512 even) ----
  {
    const unsigned short* dwBase = dwT + ((wid * 16 + row16) * 256 + kg * 8);
    f32x4 la = {0.f, 0.f, 0.f, 0.f};
#pragma unroll
    for (int k = 0; k < 8; ++k) {
      uint4 hf  = *(const uint4*)(lds + rowB + ((((unsigned)(k * 64)) + kgo) ^ swz));
      uint4 afd = *(const uint4*)(dwBase + k * 32);
      la = __builtin_amdgcn_mfma_f32_16x16x32_bf16(as_bf(afd), as_bf(hf), la, 0, 0, 0);
    }
#pragma unroll
    for (int r = 0; r < 4; ++r) {
      int cls = wid * 16 + kg * 4 + r;
      l_lds[row16][cls] = la[r] + dense_b[cls];
    }
  }
  __syncthreads();

  {
    int r = tid >> 5, cg = tid & 31;   // 16 rows x 32 col-groups of 4
    float4 v = *(const float4*)&l_lds[r][cg * 4];
    float mx = fmaxf(fmaxf(v.x, v.y), fmaxf(v.z, v.w));
#pragma unroll
    for (int sh = 1; sh < 32; sh <<= 1) mx = fmaxf(mx, __shfl_xor(mx, sh));
    const float L2E = 1.4426950408889634f;
    float e0 = __builtin_amdgcn_exp2f((v.x - mx) * L2E);
    float e1 = __builtin_amdgcn_exp2f((v.y - mx) * L2E);
    float e2 = __builtin_amdgcn_exp2f((v.z - mx) * L2E);
    float e3 = __builtin_amdgcn_exp2f((v.w - mx) * L2E);
    float sm = e0 + e1 + e2 + e3;
#pragma unroll
    for (int sh = 1; sh < 32; sh <<= 1) sm += __shfl_xor(sm, sh);
    float inv = __builtin_amdgcn_rcpf(sm);
    float4 o = {e0 * inv, e1 * inv, e2 * inv, e3 * inv};
    *(float4*)&out[(rbase + r) * 128 + cg * 4] = o;
  }
}

extern "C" void kernel_launch(void* const* d_in, const int* in_sizes, int n_in,
                              void* d_out, int out_size, void* d_ws, size_t ws_size,
                              hipStream_t stream) {
  const int*   x      = (const int*)d_in[0];    // [1024][512] int32
  const float* kern   = (const float*)d_in[1];  // [128][1024]
  const float* rec    = (const float*)d_in[2];  // [256][1024]
  const float* bias   = (const float*)d_in[3];  // [1024]
  const float* dw     = (const float*)d_in[4];  // [256][128]
  const float* db     = (const float*)d_in[5];  // [128]
  float* outp = (float*)d_out;                  // [1024][128]

  unsigned char* ws = (unsigned char*)d_ws;
  unsigned short* recT = (unsigned short*)(ws);            // 512 KB
  unsigned short* kb2  = (unsigned short*)(ws + 524288);   // 256 KB
  unsigned short* dwT  = (unsigned short*)(ws + 786432);   //  64 KB

  prep_kernel<<<1664, 256, 0, stream>>>(rec, kern, bias, dw, recT, kb2, dwT);
  lstm_kernel<<<64, 512, 0, stream>>>(recT, kb2, dwT, x, db, outp);
}